// Round 1
// baseline (913.265 us; speedup 1.0000x reference)
//
#include <hip/hip_runtime.h>

#define BB 4
#define CCH 256
#define OCH 256
#define HH 64
#define WW 64
#define HWSZ 4096
#define KKN 9

// ---------------------------------------------------------------------------
// Kernel 1: transpose w_off [27][C][9] -> WT [C][9][28]  (j padded 27->28, 0)
// ---------------------------------------------------------------------------
__global__ void k_transpose(const float* __restrict__ w_off, float* __restrict__ WT) {
    int i = blockIdx.x * blockDim.x + threadIdx.x;
    if (i >= CCH * 9 * 28) return;
    int c = i / 252;
    int r = i % 252;
    int t = r / 28;
    int j = r % 28;
    WT[i] = (j < 27) ? w_off[((size_t)j * CCH + c) * 9 + t] : 0.0f;
}

// ---------------------------------------------------------------------------
// Kernel 2: pred conv (C=256 in, 27 out, 3x3, pad 1) -> P[b][27][HW]
// sigmoid applied to channels 18..26 (mask). grid = B*H, block = 256.
// thread = (px = tid&63, cq = tid>>6 -> 64-channel quarter)
// ---------------------------------------------------------------------------
__global__ __launch_bounds__(256) void k_pred(const float* __restrict__ x,
                                              const float* __restrict__ WT,
                                              const float* __restrict__ b_off,
                                              float* __restrict__ P) {
    int b = blockIdx.x / HH;
    int h = blockIdx.x % HH;
    int tid = threadIdx.x;
    int px = tid & 63;
    int cq = tid >> 6;   // 0..3

    float4 acc[7];
#pragma unroll
    for (int qk = 0; qk < 7; ++qk) acc[qk] = make_float4(0.f, 0.f, 0.f, 0.f);

    for (int cc = 0; cc < 64; ++cc) {
        int c = cq * 64 + cc;
        const float* xp = x + ((size_t)b * CCH + c) * HWSZ;
        float xv[9];
#pragma unroll
        for (int t = 0; t < 9; ++t) {
            int dy = t / 3 - 1, dx = t % 3 - 1;
            int y = h + dy, xw = px + dx;
            bool ok = (y >= 0 && y < HH && xw >= 0 && xw < WW);
            xv[t] = ok ? xp[y * WW + xw] : 0.0f;
        }
        const float4* wp = (const float4*)(WT + (size_t)c * 252);
#pragma unroll
        for (int t = 0; t < 9; ++t) {
#pragma unroll
            for (int qk = 0; qk < 7; ++qk) {
                float4 wv = wp[t * 7 + qk];
                acc[qk].x += xv[t] * wv.x;
                acc[qk].y += xv[t] * wv.y;
                acc[qk].z += xv[t] * wv.z;
                acc[qk].w += xv[t] * wv.w;
            }
        }
    }

    __shared__ float buf[64][28];
    if (cq == 0) {
#pragma unroll
        for (int qk = 0; qk < 7; ++qk) *(float4*)&buf[px][qk * 4] = acc[qk];
    }
    __syncthreads();
    for (int wv = 1; wv < 4; ++wv) {
        if (cq == wv) {
#pragma unroll
            for (int qk = 0; qk < 7; ++qk) {
                float4 cur = *(float4*)&buf[px][qk * 4];
                cur.x += acc[qk].x; cur.y += acc[qk].y;
                cur.z += acc[qk].z; cur.w += acc[qk].w;
                *(float4*)&buf[px][qk * 4] = cur;
            }
        }
        __syncthreads();
    }

    // finish: thread -> (px, jg): j = jg*7 .. +7
    int jg = tid >> 6;
#pragma unroll
    for (int qk = 0; qk < 7; ++qk) {
        int j = jg * 7 + qk;
        if (j < 27) {
            float v = buf[px][j] + b_off[j];
            if (j >= 18) v = 1.0f / (1.0f + expf(-v));
            P[((size_t)b * 27 + j) * HWSZ + h * WW + px] = v;
        }
    }
}

// ---------------------------------------------------------------------------
// Kernel 3: deformable sampling + GEMM.
// grid = B*H (one row of 64 px), block = 256.
// Output tile per block: 256 o x 64 px. Thread tile 8x8 (to = tid>>3, tp = tid&7).
// K loop over channels in chunks of 4 (36 ck-steps per chunk).
// val[f][px] staged in LDS (producer: lane = px, wave-uniform f).
// w2[f][o] staged in LDS from w_def (36 contiguous floats per o per chunk).
// Per-thread sampling descriptors (wgt*mask, clamped addr + plane offset)
// computed ONCE into registers: each thread owns 9 fixed (f%36 -> k, px) items.
// ---------------------------------------------------------------------------
__global__ __launch_bounds__(256) void k_deform(const float* __restrict__ x,
                                                const float* __restrict__ P,
                                                const float* __restrict__ w_def,
                                                const float* __restrict__ b_def,
                                                float* __restrict__ out) {
    int b = blockIdx.x / HH;
    int h = blockIdx.x % HH;
    int tid = threadIdx.x;
    int px = tid & 63;
    int q  = tid >> 6;   // 0..3

    __shared__ float val_lds[36][64];   //  9216 B
    __shared__ float w2_lds[36][256];   // 36864 B

    // --- per-thread sampling descriptors (fixed across all channel chunks) ---
    float wreg[9][4];
    int   areg[9][4];   // plane address + (f/9)*HWSZ folded in
    {
        const float* Pb = P + (size_t)b * 27 * HWSZ + h * WW + px;
#pragma unroll
        for (int r = 0; r < 9; ++r) {
            int f = q + 4 * r;          // 0..35, each (f,px) owned by exactly one thread
            int k = f % 9;
            int ccc = f / 9;            // 0..3 within chunk
            float offy = Pb[(2 * k) * HWSZ];
            float offx = Pb[(2 * k + 1) * HWSZ];
            float m    = Pb[(18 + k) * HWSZ];
            float sy = offy + (float)(h + k / 3 - 1);
            float sx = offx + (float)(px + k % 3 - 1);
            float y0f = floorf(sy), x0f = floorf(sx);
            float ty = sy - y0f, tx = sx - x0f;
            int y0 = (int)y0f, x0 = (int)x0f;
#pragma unroll
            for (int dy = 0; dy < 2; ++dy) {
#pragma unroll
                for (int dx = 0; dx < 2; ++dx) {
                    int yi = y0 + dy, xi = x0 + dx;
                    bool ok = (yi >= 0 && yi < HH && xi >= 0 && xi < WW);
                    float wgt = (dy ? ty : 1.0f - ty) * (dx ? tx : 1.0f - tx) * m;
                    wreg[r][dy * 2 + dx] = ok ? wgt : 0.0f;
                    areg[r][dy * 2 + dx] = (ok ? (yi * WW + xi) : 0) + ccc * HWSZ;
                }
            }
        }
    }

    const float* xb = x + (size_t)b * CCH * HWSZ;

    int tp = tid & 7;
    int to = tid >> 3;
    int px0 = tp * 8;
    int o0  = to * 8;

    float acc[8][8];
#pragma unroll
    for (int i = 0; i < 8; ++i)
#pragma unroll
        for (int j = 0; j < 8; ++j) acc[i][j] = 0.0f;

    for (int cb = 0; cb < CCH; cb += 4) {
        // --- stage w2 chunk: w2_lds[f][o], f = cc*9 + k ---
#pragma unroll
        for (int r2 = 0; r2 < 9; ++r2) {
            int i = tid + r2 * 256;         // i = o*9 + qq
            int o = i / 9;
            int qq = i - o * 9;
            float4 f4 = *(const float4*)(w_def + (size_t)o * 2304 + cb * 9 + qq * 4);
            int ff = qq * 4;
            w2_lds[ff + 0][o] = f4.x;
            w2_lds[ff + 1][o] = f4.y;
            w2_lds[ff + 2][o] = f4.z;
            w2_lds[ff + 3][o] = f4.w;
        }
        // --- stage val chunk: val_lds[f][px] ---
        {
            const float* xp = xb + (size_t)cb * HWSZ;
#pragma unroll
            for (int r = 0; r < 9; ++r) {
                float v = xp[areg[r][0]] * wreg[r][0]
                        + xp[areg[r][1]] * wreg[r][1]
                        + xp[areg[r][2]] * wreg[r][2]
                        + xp[areg[r][3]] * wreg[r][3];
                val_lds[q + 4 * r][px] = v;
            }
        }
        __syncthreads();
        // --- GEMM micro-step: 36 ck x (8o x 8px) ---
#pragma unroll 4
        for (int f = 0; f < 36; ++f) {
            float4 vr0 = *(const float4*)&val_lds[f][px0];
            float4 vr1 = *(const float4*)&val_lds[f][px0 + 4];
            float4 wc0 = *(const float4*)&w2_lds[f][o0];
            float4 wc1 = *(const float4*)&w2_lds[f][o0 + 4];
            float wr[8] = {wc0.x, wc0.y, wc0.z, wc0.w, wc1.x, wc1.y, wc1.z, wc1.w};
            float vv[8] = {vr0.x, vr0.y, vr0.z, vr0.w, vr1.x, vr1.y, vr1.z, vr1.w};
#pragma unroll
            for (int i = 0; i < 8; ++i)
#pragma unroll
                for (int j = 0; j < 8; ++j)
                    acc[i][j] += wr[i] * vv[j];
        }
        __syncthreads();
    }

    // epilogue
#pragma unroll
    for (int i = 0; i < 8; ++i) {
        int o = o0 + i;
        float bd = b_def[o];
        float* op = out + ((size_t)b * OCH + o) * HWSZ + h * WW + px0;
        float4 s0 = make_float4(acc[i][0] + bd, acc[i][1] + bd, acc[i][2] + bd, acc[i][3] + bd);
        float4 s1 = make_float4(acc[i][4] + bd, acc[i][5] + bd, acc[i][6] + bd, acc[i][7] + bd);
        *(float4*)op = s0;
        *(float4*)(op + 4) = s1;
    }
}

// ---------------------------------------------------------------------------
extern "C" void kernel_launch(void* const* d_in, const int* in_sizes, int n_in,
                              void* d_out, int out_size, void* d_ws, size_t ws_size,
                              hipStream_t stream) {
    const float* x     = (const float*)d_in[0];
    const float* w_off = (const float*)d_in[1];
    const float* b_off = (const float*)d_in[2];
    const float* w_def = (const float*)d_in[3];
    const float* b_def = (const float*)d_in[4];
    float* out = (float*)d_out;

    float* P  = (float*)d_ws;                          // B*27*HW = 442368 floats
    float* WT = P + (size_t)BB * 27 * HWSZ;            // 64512 floats

    hipLaunchKernelGGL(k_transpose, dim3(252), dim3(256), 0, stream, w_off, WT);
    hipLaunchKernelGGL(k_pred, dim3(BB * HH), dim3(256), 0, stream, x, WT, b_off, P);
    hipLaunchKernelGGL(k_deform, dim3(BB * HH), dim3(256), 0, stream, x, P, w_def, b_def, out);
}

// Round 2
// 353.069 us; speedup vs baseline: 2.5866x; 2.5866x over previous
//
#include <hip/hip_runtime.h>

#define BB 4
#define CCH 256
#define OCH 256
#define HH 64
#define WW 64
#define HWSZ 4096

typedef __bf16 bf16_t;
typedef bf16_t bf16x8 __attribute__((ext_vector_type(8)));
typedef float f32x4 __attribute__((ext_vector_type(4)));

__device__ __forceinline__ unsigned int bpack(float a, float b) {
    unsigned int ua = __float_as_uint(a);
    ua = (ua + 0x7FFFu + ((ua >> 16) & 1u)) >> 16;
    unsigned int ub = __float_as_uint(b);
    ub = (ub + 0x7FFFu + ((ub >> 16) & 1u)) >> 16;
    return ua | (ub << 16);
}

// ---------------------------------------------------------------------------
// Kernel 1: transpose w_off [27][C][9] -> WT [C][9][28]  (j padded 27->28, 0)
// ---------------------------------------------------------------------------
__global__ void k_transpose(const float* __restrict__ w_off, float* __restrict__ WT) {
    int i = blockIdx.x * blockDim.x + threadIdx.x;
    if (i >= CCH * 9 * 28) return;
    int c = i / 252;
    int r = i % 252;
    int t = r / 28;
    int j = r % 28;
    WT[i] = (j < 27) ? w_off[((size_t)j * CCH + c) * 9 + t] : 0.0f;
}

// ---------------------------------------------------------------------------
// Kernel 1b: w_def [O][C][9] -> w2F bf16 frag-major [9 k][32 cg][256 o][8 j]
//            row r = k*32+cg holds c = cg*8+j. 589824 elements.
// ---------------------------------------------------------------------------
__global__ void k_w2f(const float* __restrict__ w_def, ushort* __restrict__ w2F) {
    int i = blockIdx.x * blockDim.x + threadIdx.x;
    if (i >= 9 * 32 * 256 * 8) return;
    int j = i & 7;
    int o = (i >> 3) & 255;
    int cg = (i >> 11) & 31;
    int k = i >> 16;
    int c = cg * 8 + j;
    float v = w_def[(size_t)o * 2304 + c * 9 + k];
    unsigned int u = __float_as_uint(v);
    u = (u + 0x7FFFu + ((u >> 16) & 1u)) >> 16;
    w2F[i] = (ushort)u;
}

// ---------------------------------------------------------------------------
// Kernel 2: pred conv (C=256 in, 27 out, 3x3, pad 1) -> P[b][27][HW]  (fp32)
// ---------------------------------------------------------------------------
__global__ __launch_bounds__(256) void k_pred(const float* __restrict__ x,
                                              const float* __restrict__ WT,
                                              const float* __restrict__ b_off,
                                              float* __restrict__ P) {
    int b = blockIdx.x / HH;
    int h = blockIdx.x % HH;
    int tid = threadIdx.x;
    int px = tid & 63;
    int cq = tid >> 6;

    float4 acc[7];
#pragma unroll
    for (int qk = 0; qk < 7; ++qk) acc[qk] = make_float4(0.f, 0.f, 0.f, 0.f);

    for (int cc = 0; cc < 64; ++cc) {
        int c = cq * 64 + cc;
        const float* xp = x + ((size_t)b * CCH + c) * HWSZ;
        float xv[9];
#pragma unroll
        for (int t = 0; t < 9; ++t) {
            int dy = t / 3 - 1, dx = t % 3 - 1;
            int y = h + dy, xw = px + dx;
            bool ok = (y >= 0 && y < HH && xw >= 0 && xw < WW);
            xv[t] = ok ? xp[y * WW + xw] : 0.0f;
        }
        const float4* wp = (const float4*)(WT + (size_t)c * 252);
#pragma unroll
        for (int t = 0; t < 9; ++t) {
#pragma unroll
            for (int qk = 0; qk < 7; ++qk) {
                float4 wv = wp[t * 7 + qk];
                acc[qk].x += xv[t] * wv.x;
                acc[qk].y += xv[t] * wv.y;
                acc[qk].z += xv[t] * wv.z;
                acc[qk].w += xv[t] * wv.w;
            }
        }
    }

    __shared__ float buf[64][28];
    if (cq == 0) {
#pragma unroll
        for (int qk = 0; qk < 7; ++qk) *(float4*)&buf[px][qk * 4] = acc[qk];
    }
    __syncthreads();
    for (int wv = 1; wv < 4; ++wv) {
        if (cq == wv) {
#pragma unroll
            for (int qk = 0; qk < 7; ++qk) {
                float4 cur = *(float4*)&buf[px][qk * 4];
                cur.x += acc[qk].x; cur.y += acc[qk].y;
                cur.z += acc[qk].z; cur.w += acc[qk].w;
                *(float4*)&buf[px][qk * 4] = cur;
            }
        }
        __syncthreads();
    }

    int jg = tid >> 6;
#pragma unroll
    for (int qk = 0; qk < 7; ++qk) {
        int j = jg * 7 + qk;
        if (j < 27) {
            float v = buf[px][j] + b_off[j];
            if (j >= 18) v = 1.0f / (1.0f + expf(-v));
            P[((size_t)b * 27 + j) * HWSZ + h * WW + px] = v;
        }
    }
}

// ---------------------------------------------------------------------------
// Kernel 3: deformable sampling + bf16 MFMA GEMM.
// grid = 512: blk -> px0=(blk&1)*32, h=(blk>>1)&63, b=blk>>7.
// block = 256 thr (4 waves). Tile: 256 o x 32 px, K = 2304 (k-major: k*256+c).
// 72 chunks of 32 c (fixed k per chunk). B (val) staged in LDS in frag order,
// double-buffered; A (w2F) read per-wave from L2 in frag order.
// ---------------------------------------------------------------------------
__global__ __launch_bounds__(256) void k_deform2(const float* __restrict__ x,
                                                 const float* __restrict__ P,
                                                 const ushort* __restrict__ w2F,
                                                 const float* __restrict__ b_def,
                                                 float* __restrict__ out) {
    int blk = blockIdx.x;
    int px0 = (blk & 1) * 32;
    int h   = (blk >> 1) & 63;
    int b   = blk >> 7;
    int tid = threadIdx.x;
    // staging role
    int spx  = tid & 31;
    int sgrp = tid >> 5;          // 0..7 -> cc0 = sgrp*4
    int pxg  = px0 + spx;
    // mfma role
    int lane = tid & 63;
    int wm   = tid >> 6;          // o block = wm*64
    int l16  = lane & 15;
    int lq   = lane >> 4;

    __shared__ ushort b_lds[2][4][2][16][8];   // [buf][kg][nt][px16][j]  8KB

    const float* xb = x + (size_t)b * CCH * HWSZ;
    const bf16x8* w2v = (const bf16x8*)w2F;

    f32x4 acc[4][2];
#pragma unroll
    for (int mf = 0; mf < 4; ++mf)
#pragma unroll
        for (int nf = 0; nf < 2; ++nf) acc[mf][nf] = (f32x4){0.f, 0.f, 0.f, 0.f};

    float wgt[4];
    int aoff[4];
    const float* Pb = P + (size_t)b * 27 * HWSZ + h * WW + pxg;

    auto make_desc = [&](int k) {
        float offy = Pb[(size_t)(2 * k) * HWSZ];
        float offx = Pb[(size_t)(2 * k + 1) * HWSZ];
        float m    = Pb[(size_t)(18 + k) * HWSZ];
        float sy = offy + (float)(h + k / 3 - 1);
        float sx = offx + (float)(pxg + k % 3 - 1);
        float y0f = floorf(sy), x0f = floorf(sx);
        float ty = sy - y0f, tx = sx - x0f;
        int y0 = (int)y0f, x0 = (int)x0f;
#pragma unroll
        for (int dy = 0; dy < 2; ++dy) {
#pragma unroll
            for (int dx = 0; dx < 2; ++dx) {
                int yi = y0 + dy, xi = x0 + dx;
                bool ok = (yi >= 0 && yi < HH && xi >= 0 && xi < WW);
                float wg = (dy ? ty : 1.0f - ty) * (dx ? tx : 1.0f - tx) * m;
                wgt[dy * 2 + dx]  = ok ? wg : 0.0f;
                aoff[dy * 2 + dx] = ok ? (yi * WW + xi) : 0;
            }
        }
    };

    make_desc(0);
    // prologue: stage chunk 0 into buf 0
    {
        const float* xp = xb + (size_t)(sgrp * 4) * HWSZ;
        float g[4][4];
#pragma unroll
        for (int i = 0; i < 4; ++i)
#pragma unroll
            for (int j = 0; j < 4; ++j) g[i][j] = xp[(size_t)i * HWSZ + aoff[j]];
        float v[4];
#pragma unroll
        for (int i = 0; i < 4; ++i)
            v[i] = g[i][0] * wgt[0] + g[i][1] * wgt[1] + g[i][2] * wgt[2] + g[i][3] * wgt[3];
        unsigned int* dst = (unsigned int*)&b_lds[0][sgrp >> 1][spx >> 4][spx & 15][(sgrp & 1) * 4];
        dst[0] = bpack(v[0], v[1]);
        dst[1] = bpack(v[2], v[3]);
    }
    bf16x8 aCur[4];
#pragma unroll
    for (int mf = 0; mf < 4; ++mf)
        aCur[mf] = w2v[(size_t)lq * 256 + wm * 64 + mf * 16 + l16];
    __syncthreads();

#pragma unroll 2
    for (int t = 0; t < 72; ++t) {
        int cur = t & 1;
        bool pf = (t < 71);
        bf16x8 aNxt[4];
        float g[4][4];
        if (pf) {
            int tn = t + 1;
            int kn = tn >> 3;
            int cg0 = (tn & 7) * 4;
            int row = kn * 32 + cg0 + lq;
#pragma unroll
            for (int mf = 0; mf < 4; ++mf)
                aNxt[mf] = w2v[(size_t)row * 256 + wm * 64 + mf * 16 + l16];
            if ((tn & 7) == 0) make_desc(kn);
            const float* xp = xb + (size_t)((tn & 7) * 32 + sgrp * 4) * HWSZ;
#pragma unroll
            for (int i = 0; i < 4; ++i)
#pragma unroll
                for (int j = 0; j < 4; ++j) g[i][j] = xp[(size_t)i * HWSZ + aoff[j]];
        }
        bf16x8 b0 = *(const bf16x8*)&b_lds[cur][lq][0][l16][0];
        bf16x8 b1 = *(const bf16x8*)&b_lds[cur][lq][1][l16][0];
#pragma unroll
        for (int mf = 0; mf < 4; ++mf) {
            acc[mf][0] = __builtin_amdgcn_mfma_f32_16x16x32_bf16(aCur[mf], b0, acc[mf][0], 0, 0, 0);
            acc[mf][1] = __builtin_amdgcn_mfma_f32_16x16x32_bf16(aCur[mf], b1, acc[mf][1], 0, 0, 0);
        }
        if (pf) {
            float v[4];
#pragma unroll
            for (int i = 0; i < 4; ++i)
                v[i] = g[i][0] * wgt[0] + g[i][1] * wgt[1] + g[i][2] * wgt[2] + g[i][3] * wgt[3];
            unsigned int* dst = (unsigned int*)&b_lds[cur ^ 1][sgrp >> 1][spx >> 4][spx & 15][(sgrp & 1) * 4];
            dst[0] = bpack(v[0], v[1]);
            dst[1] = bpack(v[2], v[3]);
        }
        __syncthreads();
        if (pf) {
#pragma unroll
            for (int mf = 0; mf < 4; ++mf) aCur[mf] = aNxt[mf];
        }
    }

    // epilogue
#pragma unroll
    for (int mf = 0; mf < 4; ++mf) {
#pragma unroll
        for (int nf = 0; nf < 2; ++nf) {
#pragma unroll
            for (int r = 0; r < 4; ++r) {
                int o = wm * 64 + mf * 16 + lq * 4 + r;
                float bd = b_def[o];
                out[((size_t)b * OCH + o) * HWSZ + h * WW + px0 + nf * 16 + l16] = acc[mf][nf][r] + bd;
            }
        }
    }
}

// ---------------------------------------------------------------------------
extern "C" void kernel_launch(void* const* d_in, const int* in_sizes, int n_in,
                              void* d_out, int out_size, void* d_ws, size_t ws_size,
                              hipStream_t stream) {
    const float* x     = (const float*)d_in[0];
    const float* w_off = (const float*)d_in[1];
    const float* b_off = (const float*)d_in[2];
    const float* w_def = (const float*)d_in[3];
    const float* b_def = (const float*)d_in[4];
    float* out = (float*)d_out;

    float*  P   = (float*)d_ws;                 // 442368 floats
    float*  WT  = P + (size_t)BB * 27 * HWSZ;   // 64512 floats
    ushort* w2F = (ushort*)(WT + 64512);        // 589824 ushorts (bf16)

    hipLaunchKernelGGL(k_transpose, dim3(252), dim3(256), 0, stream, w_off, WT);
    hipLaunchKernelGGL(k_w2f, dim3(2304), dim3(256), 0, stream, w_def, w2F);
    hipLaunchKernelGGL(k_pred, dim3(BB * HH), dim3(256), 0, stream, x, WT, b_off, P);
    hipLaunchKernelGGL(k_deform2, dim3(512), dim3(256), 0, stream, x, P, w2F, b_def, out);
}

// Round 3
// 169.755 us; speedup vs baseline: 5.3799x; 2.0799x over previous
//
#include <hip/hip_runtime.h>

#define BB 4
#define CCH 256
#define OCH 256
#define HH 64
#define WW 64
#define HWSZ 4096

typedef __bf16 bf16_t;
typedef bf16_t bf16x8 __attribute__((ext_vector_type(8)));
typedef float f32x4 __attribute__((ext_vector_type(4)));

__device__ __forceinline__ unsigned int bpack(float a, float b) {
    unsigned int ua = __float_as_uint(a);
    ua = (ua + 0x7FFFu + ((ua >> 16) & 1u)) >> 16;
    unsigned int ub = __float_as_uint(b);
    ub = (ub + 0x7FFFu + ((ub >> 16) & 1u)) >> 16;
    return ua | (ub << 16);
}

// ---------------------------------------------------------------------------
// Kernel 1a: w_off [27][C][9] -> w1F bf16 frag-major [9 k][32 cSub][32 o][8 j]
//            row r = k*32+cSub holds c = cSub*8+j ; o rows 27..31 zero.
// ---------------------------------------------------------------------------
__global__ void k_w1f(const float* __restrict__ w_off, ushort* __restrict__ w1F) {
    int i = blockIdx.x * blockDim.x + threadIdx.x;
    if (i >= 9 * 32 * 32 * 8) return;
    int j = i & 7;
    int o = (i >> 3) & 31;
    int cSub = (i >> 8) & 31;
    int k = i >> 13;
    float v = 0.0f;
    if (o < 27) v = w_off[((size_t)o * CCH + cSub * 8 + j) * 9 + k];
    unsigned int u = __float_as_uint(v);
    u = (u + 0x7FFFu + ((u >> 16) & 1u)) >> 16;
    w1F[i] = (ushort)u;
}

// ---------------------------------------------------------------------------
// Kernel 1b: w_def [O][C][9] -> w2F bf16 frag-major [9 k][32 cg][256 o][8 j]
// ---------------------------------------------------------------------------
__global__ void k_w2f(const float* __restrict__ w_def, ushort* __restrict__ w2F) {
    int i = blockIdx.x * blockDim.x + threadIdx.x;
    if (i >= 9 * 32 * 256 * 8) return;
    int j = i & 7;
    int o = (i >> 3) & 255;
    int cg = (i >> 11) & 31;
    int k = i >> 16;
    int c = cg * 8 + j;
    float v = w_def[(size_t)o * 2304 + c * 9 + k];
    unsigned int u = __float_as_uint(v);
    u = (u + 0x7FFFu + ((u >> 16) & 1u)) >> 16;
    w2F[i] = (ushort)u;
}

// ---------------------------------------------------------------------------
// Kernel 2: pred conv via MFMA. Tile: 32 o (27 used) x 64 px, K split 4 ways
// across blocks (each block: 2 channel-groups of 32 x 9 taps = 18 chunks).
// grid = 1024: blk -> g = blk&3, h = (blk>>2)&63, b = blk>>8. block = 256.
// Accumulates raw conv into P via atomicAdd (P zeroed by memset beforehand).
// ---------------------------------------------------------------------------
__global__ __launch_bounds__(256) void k_pred2(const float* __restrict__ x,
                                               const ushort* __restrict__ w1F,
                                               float* __restrict__ P) {
    int blk = blockIdx.x;
    int g = blk & 3;
    int h = (blk >> 2) & 63;
    int b = blk >> 8;
    int tid = threadIdx.x;
    // staging role
    int spx  = tid & 63;
    int sgrp = tid >> 6;       // c_local = sgrp*8 + j
    // mfma role
    int lane = tid & 63;
    int wv   = tid >> 6;       // px quarter
    int l16  = lane & 15;
    int lq   = lane >> 4;

    __shared__ ushort b_lds[2][4][4][16][8];   // [buf][kg][nt][px16][j]  8KB

    const float* xb = x + (size_t)b * CCH * HWSZ;
    const bf16x8* w1v = (const bf16x8*)w1F;

    f32x4 acc[2];
    acc[0] = (f32x4){0.f, 0.f, 0.f, 0.f};
    acc[1] = (f32x4){0.f, 0.f, 0.f, 0.f};

    // chunk t: cg = 2g + (t>=9), k = t%9
    auto stage = [&](int t, int buf) {
        int cg = 2 * g + (t >= 9);
        int k  = t % 9 >= 9 ? 0 : t % 9;   // t%9
        k = t - (t >= 9 ? 9 : 0);
        int y   = h + k / 3 - 1;
        int pxs = spx + k % 3 - 1;
        bool ok = (y >= 0 && y < HH && pxs >= 0 && pxs < WW);
        const float* xp = xb + (size_t)(cg * 32 + sgrp * 8) * HWSZ + y * WW + pxs;
        float v[8];
#pragma unroll
        for (int j = 0; j < 8; ++j) v[j] = ok ? xp[(size_t)j * HWSZ] : 0.0f;
        uint4 d;
        d.x = bpack(v[0], v[1]);
        d.y = bpack(v[2], v[3]);
        d.z = bpack(v[4], v[5]);
        d.w = bpack(v[6], v[7]);
        *(uint4*)&b_lds[buf][sgrp][spx >> 4][spx & 15][0] = d;
    };

    stage(0, 0);
    __syncthreads();

    for (int t = 0; t < 18; ++t) {
        int cur = t & 1;
        int cg = 2 * g + (t >= 9);
        int k  = t - (t >= 9 ? 9 : 0);
        // A frags (from L2, frag-major)
        int row = k * 32 + cg * 4 + lq;
        bf16x8 a0 = w1v[(size_t)row * 32 + 0 * 16 + l16];
        bf16x8 a1 = w1v[(size_t)row * 32 + 1 * 16 + l16];
        if (t < 17) stage(t + 1, cur ^ 1);
        bf16x8 bfrag = *(const bf16x8*)&b_lds[cur][lq][wv][l16][0];
        acc[0] = __builtin_amdgcn_mfma_f32_16x16x32_bf16(a0, bfrag, acc[0], 0, 0, 0);
        acc[1] = __builtin_amdgcn_mfma_f32_16x16x32_bf16(a1, bfrag, acc[1], 0, 0, 0);
        __syncthreads();
    }

    // epilogue: atomic accumulate raw conv. C/D: col=l16 (px), row=lq*4+r (+16*mf)
#pragma unroll
    for (int mf = 0; mf < 2; ++mf) {
#pragma unroll
        for (int r = 0; r < 4; ++r) {
            int o = mf * 16 + lq * 4 + r;
            if (o < 27) {
                atomicAdd(&P[((size_t)b * 27 + o) * HWSZ + h * WW + wv * 16 + l16],
                          acc[mf][r]);
            }
        }
    }
}

// ---------------------------------------------------------------------------
// Kernel 2b: finalize P in place: + bias, sigmoid on mask planes (j>=18)
// ---------------------------------------------------------------------------
__global__ void k_pfin(float* __restrict__ P, const float* __restrict__ b_off) {
    int i = blockIdx.x * blockDim.x + threadIdx.x;
    if (i >= BB * 27 * HWSZ) return;
    int j = (i >> 12) % 27;
    float v = P[i] + b_off[j];
    if (j >= 18) v = 1.0f / (1.0f + expf(-v));
    P[i] = v;
}

// ---------------------------------------------------------------------------
// Kernel 3: deformable sampling + bf16 MFMA GEMM. (unchanged from round 2)
// ---------------------------------------------------------------------------
__global__ __launch_bounds__(256) void k_deform2(const float* __restrict__ x,
                                                 const float* __restrict__ P,
                                                 const ushort* __restrict__ w2F,
                                                 const float* __restrict__ b_def,
                                                 float* __restrict__ out) {
    int blk = blockIdx.x;
    int px0 = (blk & 1) * 32;
    int h   = (blk >> 1) & 63;
    int b   = blk >> 7;
    int tid = threadIdx.x;
    int spx  = tid & 31;
    int sgrp = tid >> 5;
    int pxg  = px0 + spx;
    int lane = tid & 63;
    int wm   = tid >> 6;
    int l16  = lane & 15;
    int lq   = lane >> 4;

    __shared__ ushort b_lds[2][4][2][16][8];

    const float* xb = x + (size_t)b * CCH * HWSZ;
    const bf16x8* w2v = (const bf16x8*)w2F;

    f32x4 acc[4][2];
#pragma unroll
    for (int mf = 0; mf < 4; ++mf)
#pragma unroll
        for (int nf = 0; nf < 2; ++nf) acc[mf][nf] = (f32x4){0.f, 0.f, 0.f, 0.f};

    float wgt[4];
    int aoff[4];
    const float* Pb = P + (size_t)b * 27 * HWSZ + h * WW + pxg;

    auto make_desc = [&](int k) {
        float offy = Pb[(size_t)(2 * k) * HWSZ];
        float offx = Pb[(size_t)(2 * k + 1) * HWSZ];
        float m    = Pb[(size_t)(18 + k) * HWSZ];
        float sy = offy + (float)(h + k / 3 - 1);
        float sx = offx + (float)(pxg + k % 3 - 1);
        float y0f = floorf(sy), x0f = floorf(sx);
        float ty = sy - y0f, tx = sx - x0f;
        int y0 = (int)y0f, x0 = (int)x0f;
#pragma unroll
        for (int dy = 0; dy < 2; ++dy) {
#pragma unroll
            for (int dx = 0; dx < 2; ++dx) {
                int yi = y0 + dy, xi = x0 + dx;
                bool ok = (yi >= 0 && yi < HH && xi >= 0 && xi < WW);
                float wg = (dy ? ty : 1.0f - ty) * (dx ? tx : 1.0f - tx) * m;
                wgt[dy * 2 + dx]  = ok ? wg : 0.0f;
                aoff[dy * 2 + dx] = ok ? (yi * WW + xi) : 0;
            }
        }
    };

    make_desc(0);
    {
        const float* xp = xb + (size_t)(sgrp * 4) * HWSZ;
        float g[4][4];
#pragma unroll
        for (int i = 0; i < 4; ++i)
#pragma unroll
            for (int j = 0; j < 4; ++j) g[i][j] = xp[(size_t)i * HWSZ + aoff[j]];
        float v[4];
#pragma unroll
        for (int i = 0; i < 4; ++i)
            v[i] = g[i][0] * wgt[0] + g[i][1] * wgt[1] + g[i][2] * wgt[2] + g[i][3] * wgt[3];
        unsigned int* dst = (unsigned int*)&b_lds[0][sgrp >> 1][spx >> 4][spx & 15][(sgrp & 1) * 4];
        dst[0] = bpack(v[0], v[1]);
        dst[1] = bpack(v[2], v[3]);
    }
    bf16x8 aCur[4];
#pragma unroll
    for (int mf = 0; mf < 4; ++mf)
        aCur[mf] = w2v[(size_t)lq * 256 + wm * 64 + mf * 16 + l16];
    __syncthreads();

#pragma unroll 2
    for (int t = 0; t < 72; ++t) {
        int cur = t & 1;
        bool pf = (t < 71);
        bf16x8 aNxt[4];
        float g[4][4];
        if (pf) {
            int tn = t + 1;
            int kn = tn >> 3;
            int cg0 = (tn & 7) * 4;
            int row = kn * 32 + cg0 + lq;
#pragma unroll
            for (int mf = 0; mf < 4; ++mf)
                aNxt[mf] = w2v[(size_t)row * 256 + wm * 64 + mf * 16 + l16];
            if ((tn & 7) == 0) make_desc(kn);
            const float* xp = xb + (size_t)((tn & 7) * 32 + sgrp * 4) * HWSZ;
#pragma unroll
            for (int i = 0; i < 4; ++i)
#pragma unroll
                for (int j = 0; j < 4; ++j) g[i][j] = xp[(size_t)i * HWSZ + aoff[j]];
        }
        bf16x8 b0 = *(const bf16x8*)&b_lds[cur][lq][0][l16][0];
        bf16x8 b1 = *(const bf16x8*)&b_lds[cur][lq][1][l16][0];
#pragma unroll
        for (int mf = 0; mf < 4; ++mf) {
            acc[mf][0] = __builtin_amdgcn_mfma_f32_16x16x32_bf16(aCur[mf], b0, acc[mf][0], 0, 0, 0);
            acc[mf][1] = __builtin_amdgcn_mfma_f32_16x16x32_bf16(aCur[mf], b1, acc[mf][1], 0, 0, 0);
        }
        if (pf) {
            float v[4];
#pragma unroll
            for (int i = 0; i < 4; ++i)
                v[i] = g[i][0] * wgt[0] + g[i][1] * wgt[1] + g[i][2] * wgt[2] + g[i][3] * wgt[3];
            unsigned int* dst = (unsigned int*)&b_lds[cur ^ 1][sgrp >> 1][spx >> 4][spx & 15][(sgrp & 1) * 4];
            dst[0] = bpack(v[0], v[1]);
            dst[1] = bpack(v[2], v[3]);
        }
        __syncthreads();
        if (pf) {
#pragma unroll
            for (int mf = 0; mf < 4; ++mf) aCur[mf] = aNxt[mf];
        }
    }

#pragma unroll
    for (int mf = 0; mf < 4; ++mf) {
#pragma unroll
        for (int nf = 0; nf < 2; ++nf) {
#pragma unroll
            for (int r = 0; r < 4; ++r) {
                int o = wm * 64 + mf * 16 + lq * 4 + r;
                float bd = b_def[o];
                out[((size_t)b * OCH + o) * HWSZ + h * WW + px0 + nf * 16 + l16] = acc[mf][nf][r] + bd;
            }
        }
    }
}

// ---------------------------------------------------------------------------
extern "C" void kernel_launch(void* const* d_in, const int* in_sizes, int n_in,
                              void* d_out, int out_size, void* d_ws, size_t ws_size,
                              hipStream_t stream) {
    const float* x     = (const float*)d_in[0];
    const float* w_off = (const float*)d_in[1];
    const float* b_off = (const float*)d_in[2];
    const float* w_def = (const float*)d_in[3];
    const float* b_def = (const float*)d_in[4];
    float* out = (float*)d_out;

    float*  P   = (float*)d_ws;                       // 442368 floats (1.77 MB)
    ushort* w1F = (ushort*)(P + (size_t)BB * 27 * HWSZ);   // 73728 bf16
    ushort* w2F = w1F + 73728;                        // 589824 bf16

    hipMemsetAsync(P, 0, (size_t)BB * 27 * HWSZ * sizeof(float), stream);
    hipLaunchKernelGGL(k_w1f, dim3(288), dim3(256), 0, stream, w_off, w1F);
    hipLaunchKernelGGL(k_w2f, dim3(2304), dim3(256), 0, stream, w_def, w2F);
    hipLaunchKernelGGL(k_pred2, dim3(1024), dim3(256), 0, stream, x, w1F, P);
    hipLaunchKernelGGL(k_pfin, dim3(1728), dim3(256), 0, stream, P, b_off);
    hipLaunchKernelGGL(k_deform2, dim3(512), dim3(256), 0, stream, x, P, w2F, b_def, out);
}